// Round 12
// baseline (413.834 us; speedup 1.0000x reference)
//
#include <hip/hip_runtime.h>

#define N_NODES 50000
#define N_EDGES 800000
#define GRID_G 782        // ceil(N_NODES/64): 64-row blocks (round-8 best GEMM shape)
#define NB_HIST 128       // histogram blocks
#define EPB (N_EDGES / NB_HIST)   // 6250 edges per hist block
#define WORDS 25000       // N_NODES/2 packed 2x16 words
#define NORMB_BLOCKS 98   // ceil(WORDS/256); each covers 512 nodes
#define TILE_LD 132       // LDS tile row stride (pad 128->132: conflict-free b128 reads)

// ---------------- fuse W3@W_out into Wf (128x2), bf = b3@W_out + b_out ----------------
__global__ __launch_bounds__(256) void k_wfuse(const float* __restrict__ W3,
                                               const float* __restrict__ Wout,
                                               const float* __restrict__ b3,
                                               const float* __restrict__ bout,
                                               float* __restrict__ Wf,
                                               float* __restrict__ bf) {
    int t = threadIdx.x;          // 256 threads: (j,c) = (t>>1, t&1)
    int j = t >> 1, c = t & 1;
    float acc = 0.f;
    for (int k = 0; k < 128; ++k)
        acc += W3[j * 128 + k] * Wout[k * 2 + c];
    Wf[j * 2 + c] = acc;
    if (t < 2) {
        float a = bout[t];
        for (int k = 0; k < 128; ++k) a += b3[k] * Wout[k * 2 + t];
        bf[t] = a;
    }
}

// ---------------- histogram degree count (no global atomics) ----------------
__global__ __launch_bounds__(256) void k_hist(const int* __restrict__ src,
                                              const int* __restrict__ dst,
                                              unsigned int* __restrict__ partO,
                                              unsigned int* __restrict__ partI) {
    __shared__ unsigned int h[12500];   // 50 KB: 25000 nodes packed 2 per word
    const int e0 = blockIdx.x * EPB;
    for (int kind = 0; kind < 2; ++kind) {
        const int* ids = kind ? dst : src;
        unsigned int* out = kind ? partI : partO;
        for (int p = 0; p < 2; ++p) {
            for (int i = threadIdx.x; i < 12500; i += 256) h[i] = 0;
            __syncthreads();
            const int base = p * 25000;
            for (int i = threadIdx.x; i < EPB; i += 256) {
                int id = ids[e0 + i] - base;
                if ((unsigned)id < 25000u)
                    atomicAdd(&h[id >> 1], (id & 1) ? 0x10000u : 1u);
            }
            __syncthreads();
            unsigned int* o = out + blockIdx.x * WORDS + p * 12500;
            for (int i = threadIdx.x; i < 12500; i += 256) o[i] = h[i];
            __syncthreads();
        }
    }
}

// ---------------- reduce partials -> degrees, norms, scan block-sums ----------------
__global__ __launch_bounds__(256) void k_normB(const unsigned int* __restrict__ partO,
                                               const unsigned int* __restrict__ partI,
                                               float* __restrict__ norm_src,
                                               float* __restrict__ norm_dst,
                                               int* __restrict__ deg_in,
                                               int* __restrict__ partials98) {
    __shared__ int sm4[4];
    int w = blockIdx.x * 256 + threadIdx.x;
    unsigned int lo_o = 0, hi_o = 0, lo_i = 0, hi_i = 0;
    if (w < WORDS) {
        for (int b = 0; b < NB_HIST; ++b) {
            unsigned int vo = partO[b * WORDS + w];
            unsigned int vi = partI[b * WORDS + w];
            lo_o += vo & 0xFFFFu; hi_o += vo >> 16;
            lo_i += vi & 0xFFFFu; hi_i += vi >> 16;
        }
        int n0 = 2 * w;
        *(float2*)&norm_src[n0] = make_float2(rsqrtf((float)max(lo_o, 1u)),
                                              rsqrtf((float)max(hi_o, 1u)));
        *(float2*)&norm_dst[n0] = make_float2(rsqrtf((float)max(lo_i, 1u)),
                                              rsqrtf((float)max(hi_i, 1u)));
        *(int2*)&deg_in[n0] = make_int2((int)lo_i, (int)hi_i);
    }
    int v = (int)(lo_i + hi_i);
#pragma unroll
    for (int off = 32; off > 0; off >>= 1) v += __shfl_down(v, off);
    int lane = threadIdx.x & 63, wv = threadIdx.x >> 6;
    if (lane == 0) sm4[wv] = v;
    __syncthreads();
    if (threadIdx.x == 0)
        partials98[blockIdx.x] = sm4[0] + sm4[1] + sm4[2] + sm4[3];
}

// ---------------- scan: exclusive prefix over deg_in (512 nodes/block) ----------------
__global__ __launch_bounds__(256) void k_scan(const int* __restrict__ deg_in,
                                              const int* __restrict__ partials98,
                                              int* __restrict__ row_start,
                                              int* __restrict__ cursor) {
    __shared__ int sm[256];
    __shared__ int carry_s;
    int t = threadIdx.x;
    if (t < 64) {
        int acc = 0;
        for (int i = t; i < blockIdx.x; i += 64) acc += partials98[i];
#pragma unroll
        for (int off = 32; off > 0; off >>= 1) acc += __shfl_down(acc, off);
        if (t == 0) carry_s = acc;
    }
    int n0 = blockIdx.x * 512 + t * 2;
    int a0 = 0, a1 = 0;
    if (n0 + 1 < N_NODES) {
        int2 d = *(const int2*)&deg_in[n0];
        a0 = d.x; a1 = d.y;
    } else if (n0 < N_NODES) {
        a0 = deg_in[n0];
    }
    sm[t] = a0 + a1;
    __syncthreads();
#pragma unroll
    for (int off = 1; off < 256; off <<= 1) {
        int tv = (t >= off) ? sm[t - off] : 0;
        __syncthreads();
        sm[t] += tv;
        __syncthreads();
    }
    int excl = sm[t] - (a0 + a1) + carry_s;
    if (n0 < N_NODES) { row_start[n0] = excl; cursor[n0] = excl; }
    if (n0 + 1 < N_NODES) { row_start[n0 + 1] = excl + a0; cursor[n0 + 1] = excl + a0; }
    if (blockIdx.x == 0 && t == 0) row_start[N_NODES] = N_EDGES;
}

// ---------------- GEMM body (round-8 best): G = X @ W, 64 rows/block ----------------
__device__ __forceinline__ void gemm_body(const float* __restrict__ X,
                                          const float* __restrict__ W,
                                          float* __restrict__ G,
                                          float* __restrict__ Wl, int bid) {
    const int tx = threadIdx.x & 15;
    const int ty = threadIdx.x >> 4;
    const int r0 = bid * 64 + ty * 4;
    const int c0 = tx * 4;

    const float* xr[4];
#pragma unroll
    for (int i = 0; i < 4; ++i) {
        int r = r0 + i; if (r > N_NODES - 1) r = N_NODES - 1;
        xr[i] = X + (size_t)r * 128;
    }

    float acc[2][4][4] = {};
    for (int kc = 0; kc < 2; ++kc) {
        __syncthreads();
#pragma unroll
        for (int it = 0; it < 8; ++it) {
            int idx = threadIdx.x * 4 + it * 1024;
            *(float4*)&Wl[idx] = *(const float4*)&W[kc * 8192 + idx];
        }
        __syncthreads();
        const int kb = kc * 64;
        float4 xa[4], xb[4];
#pragma unroll
        for (int i = 0; i < 4; ++i) xa[i] = *(const float4*)(xr[i] + kb);
#pragma unroll 2
        for (int ks = 0; ks < 64; ks += 4) {
            const int kpf = (ks + 4 < 64) ? ks + 4 : ks;
#pragma unroll
            for (int i = 0; i < 4; ++i) xb[i] = *(const float4*)(xr[i] + kb + kpf);
#pragma unroll
            for (int kk = 0; kk < 4; ++kk) {
                float4 w0 = *(const float4*)&Wl[(ks + kk) * 128 + c0];
                float4 w1 = *(const float4*)&Wl[(ks + kk) * 128 + c0 + 64];
#pragma unroll
                for (int i = 0; i < 4; ++i) {
                    float a = (kk == 0) ? xa[i].x : (kk == 1) ? xa[i].y
                             : (kk == 2) ? xa[i].z : xa[i].w;
                    acc[0][i][0] = fmaf(a, w0.x, acc[0][i][0]);
                    acc[0][i][1] = fmaf(a, w0.y, acc[0][i][1]);
                    acc[0][i][2] = fmaf(a, w0.z, acc[0][i][2]);
                    acc[0][i][3] = fmaf(a, w0.w, acc[0][i][3]);
                    acc[1][i][0] = fmaf(a, w1.x, acc[1][i][0]);
                    acc[1][i][1] = fmaf(a, w1.y, acc[1][i][1]);
                    acc[1][i][2] = fmaf(a, w1.z, acc[1][i][2]);
                    acc[1][i][3] = fmaf(a, w1.w, acc[1][i][3]);
                }
            }
#pragma unroll
            for (int i = 0; i < 4; ++i) xa[i] = xb[i];
        }
    }
#pragma unroll
    for (int i = 0; i < 4; ++i) {
        int r = r0 + i;
        if (r < N_NODES) {
            float* p = G + (size_t)r * 128 + c0;
            *(float4*)p = make_float4(acc[0][i][0], acc[0][i][1], acc[0][i][2], acc[0][i][3]);
            *(float4*)(p + 64) = make_float4(acc[1][i][0], acc[1][i][1], acc[1][i][2], acc[1][i][3]);
        }
    }
}

// ---------------- fused: GEMM1 (graph-independent) + CSR fill ----------------
__global__ __launch_bounds__(256, 4) void k_gemm_fill(const float* __restrict__ X,
                                                      const float* __restrict__ W,
                                                      float* __restrict__ G,
                                                      const int* __restrict__ src,
                                                      const int* __restrict__ dst,
                                                      const float* __restrict__ norm_src,
                                                      int* __restrict__ cursor,
                                                      int2* __restrict__ csr) {
    __shared__ float Wl[8192];
    if (blockIdx.x < GRID_G) {
        gemm_body(X, W, G, Wl, blockIdx.x);
    } else {
        int e = (blockIdx.x - GRID_G) * 256 + threadIdx.x;
        if (e < N_EDGES) {
            int d = dst[e], s = src[e];
            int pos = atomicAdd(&cursor[d], 1);
            csr[pos] = make_int2(s, __float_as_int(norm_src[s]));
        }
    }
}

// ---------------- gather (layer 1, round-8 best form): h1 = elu(nd*sum + b) ----------------
__global__ __launch_bounds__(256) void k_gather(const float* __restrict__ G,
                                                const int* __restrict__ row_start,
                                                const int2* __restrict__ csr,
                                                const float* __restrict__ norm_dst,
                                                const float* __restrict__ bias,
                                                float* __restrict__ Out) {
    int n = (blockIdx.x * 256 + threadIdx.x) >> 6;
    int lane = threadIdx.x & 63;
    if (n >= N_NODES) return;
    const int half = lane >> 5;
    const int l = lane & 31;
    int e0 = row_start[n], e1 = row_start[n + 1];
    float4 a0 = {0,0,0,0}, a1 = {0,0,0,0}, a2 = {0,0,0,0}, a3 = {0,0,0,0};
    int e = e0;
    for (; e + 8 <= e1; e += 8) {
        int2 c0 = csr[e + half],     c1 = csr[e + 2 + half];
        int2 c2 = csr[e + 4 + half], c3 = csr[e + 6 + half];
        float4 g0 = *(const float4*)(G + (size_t)c0.x * 128 + l * 4);
        float4 g1 = *(const float4*)(G + (size_t)c1.x * 128 + l * 4);
        float4 g2 = *(const float4*)(G + (size_t)c2.x * 128 + l * 4);
        float4 g3 = *(const float4*)(G + (size_t)c3.x * 128 + l * 4);
        float w0 = __int_as_float(c0.y), w1 = __int_as_float(c1.y);
        float w2 = __int_as_float(c2.y), w3 = __int_as_float(c3.y);
        a0.x = fmaf(w0, g0.x, a0.x); a0.y = fmaf(w0, g0.y, a0.y);
        a0.z = fmaf(w0, g0.z, a0.z); a0.w = fmaf(w0, g0.w, a0.w);
        a1.x = fmaf(w1, g1.x, a1.x); a1.y = fmaf(w1, g1.y, a1.y);
        a1.z = fmaf(w1, g1.z, a1.z); a1.w = fmaf(w1, g1.w, a1.w);
        a2.x = fmaf(w2, g2.x, a2.x); a2.y = fmaf(w2, g2.y, a2.y);
        a2.z = fmaf(w2, g2.z, a2.z); a2.w = fmaf(w2, g2.w, a2.w);
        a3.x = fmaf(w3, g3.x, a3.x); a3.y = fmaf(w3, g3.y, a3.y);
        a3.z = fmaf(w3, g3.z, a3.z); a3.w = fmaf(w3, g3.w, a3.w);
    }
    for (; e < e1; e += 2) {
        int idx = e + half;
        if (idx < e1) {
            int2 c = csr[idx];
            float w = __int_as_float(c.y);
            float4 g = *(const float4*)(G + (size_t)c.x * 128 + l * 4);
            a0.x = fmaf(w, g.x, a0.x); a0.y = fmaf(w, g.y, a0.y);
            a0.z = fmaf(w, g.z, a0.z); a0.w = fmaf(w, g.w, a0.w);
        }
    }
    float4 s;
    s.x = (a0.x + a1.x) + (a2.x + a3.x);
    s.y = (a0.y + a1.y) + (a2.y + a3.y);
    s.z = (a0.z + a1.z) + (a2.z + a3.z);
    s.w = (a0.w + a1.w) + (a2.w + a3.w);
    s.x += __shfl_xor(s.x, 32);
    s.y += __shfl_xor(s.y, 32);
    s.z += __shfl_xor(s.z, 32);
    s.w += __shfl_xor(s.w, 32);
    float nd = norm_dst[n];
    float4 b = *(const float4*)(bias + l * 4);
    float4 o;
    o.x = fmaf(nd, s.x, b.x);
    o.y = fmaf(nd, s.y, b.y);
    o.z = fmaf(nd, s.z, b.z);
    o.w = fmaf(nd, s.w, b.w);
    o.x = o.x > 0.f ? o.x : expm1f(o.x);
    o.y = o.y > 0.f ? o.y : expm1f(o.y);
    o.z = o.z > 0.f ? o.z : expm1f(o.z);
    o.w = o.w > 0.f ? o.w : expm1f(o.w);
    if (half == 0)
        *(float4*)(Out + (size_t)n * 128 + l * 4) = o;
}

// ---------------- fused gather+GEMM (layers 2,3): Out = act(gather(Hin) @ W + b) ----------
// Uses (D A D) h W == ((D A D) h) W: per block, gather 64 nodes' neighborhoods into an
// LDS tile (stride 132, conflict-free), then GEMM the tile by W (16 KB LDS chunks).
// Kills the GEMM's HBM X-latency (X in LDS) and the 50 MB/layer intermediate round-trip.
// PROJ (layer 3): also n_out = tile @ Wf + bf straight from the LDS tile.
template <int ELU, int PROJ>
__global__ __launch_bounds__(256, 4) void k_fused(const float* __restrict__ Hin,
                                                  const int* __restrict__ row_start,
                                                  const int2* __restrict__ csr,
                                                  const float* __restrict__ norm_dst,
                                                  const float* __restrict__ W,
                                                  const float* __restrict__ bias,
                                                  float* __restrict__ Out,
                                                  const float* __restrict__ Wf,
                                                  const float* __restrict__ bf,
                                                  float* __restrict__ proj_out) {
    __shared__ float tile[64 * TILE_LD];   // 33 KB gathered rows
    __shared__ float Wl[4096];             // 16 KB W chunk
    const int tid = threadIdx.x;
    const int bid = blockIdx.x;
    const int lane = tid & 63;
    const int wv = tid >> 6;
    const int half = lane >> 5;
    const int l = lane & 31;

    // ---- phase 1: gather 16 nodes per wave into LDS tile ----
    for (int i = 0; i < 16; ++i) {
        const int nl = wv * 16 + i;
        const int n = bid * 64 + nl;
        if (n >= N_NODES) break;
        int e0 = row_start[n], e1 = row_start[n + 1];
        float4 a0 = {0,0,0,0}, a1 = {0,0,0,0}, a2 = {0,0,0,0}, a3 = {0,0,0,0};
        int e = e0;
        for (; e + 8 <= e1; e += 8) {
            int2 c0 = csr[e + half],     c1 = csr[e + 2 + half];
            int2 c2 = csr[e + 4 + half], c3 = csr[e + 6 + half];
            float4 g0 = *(const float4*)(Hin + (size_t)c0.x * 128 + l * 4);
            float4 g1 = *(const float4*)(Hin + (size_t)c1.x * 128 + l * 4);
            float4 g2 = *(const float4*)(Hin + (size_t)c2.x * 128 + l * 4);
            float4 g3 = *(const float4*)(Hin + (size_t)c3.x * 128 + l * 4);
            float w0 = __int_as_float(c0.y), w1 = __int_as_float(c1.y);
            float w2 = __int_as_float(c2.y), w3 = __int_as_float(c3.y);
            a0.x = fmaf(w0, g0.x, a0.x); a0.y = fmaf(w0, g0.y, a0.y);
            a0.z = fmaf(w0, g0.z, a0.z); a0.w = fmaf(w0, g0.w, a0.w);
            a1.x = fmaf(w1, g1.x, a1.x); a1.y = fmaf(w1, g1.y, a1.y);
            a1.z = fmaf(w1, g1.z, a1.z); a1.w = fmaf(w1, g1.w, a1.w);
            a2.x = fmaf(w2, g2.x, a2.x); a2.y = fmaf(w2, g2.y, a2.y);
            a2.z = fmaf(w2, g2.z, a2.z); a2.w = fmaf(w2, g2.w, a2.w);
            a3.x = fmaf(w3, g3.x, a3.x); a3.y = fmaf(w3, g3.y, a3.y);
            a3.z = fmaf(w3, g3.z, a3.z); a3.w = fmaf(w3, g3.w, a3.w);
        }
        for (; e < e1; e += 2) {
            int idx = e + half;
            if (idx < e1) {
                int2 c = csr[idx];
                float w = __int_as_float(c.y);
                float4 g = *(const float4*)(Hin + (size_t)c.x * 128 + l * 4);
                a0.x = fmaf(w, g.x, a0.x); a0.y = fmaf(w, g.y, a0.y);
                a0.z = fmaf(w, g.z, a0.z); a0.w = fmaf(w, g.w, a0.w);
            }
        }
        float4 s;
        s.x = (a0.x + a1.x) + (a2.x + a3.x);
        s.y = (a0.y + a1.y) + (a2.y + a3.y);
        s.z = (a0.z + a1.z) + (a2.z + a3.z);
        s.w = (a0.w + a1.w) + (a2.w + a3.w);
        s.x += __shfl_xor(s.x, 32);
        s.y += __shfl_xor(s.y, 32);
        s.z += __shfl_xor(s.z, 32);
        s.w += __shfl_xor(s.w, 32);
        float nd = norm_dst[n];
        if (half == 0) {
            *(float4*)&tile[nl * TILE_LD + l * 4] =
                make_float4(nd * s.x, nd * s.y, nd * s.z, nd * s.w);
        }
    }
    __syncthreads();

    // ---- phase 2: GEMM tile(64x128, LDS) @ W(128x128) + b, activation, store ----
    const int tx = tid & 15;
    const int ty = tid >> 4;
    const int c0 = tx * 4;
    float acc[2][4][4] = {};
    for (int kc = 0; kc < 4; ++kc) {
        __syncthreads();
#pragma unroll
        for (int it = 0; it < 4; ++it) {
            int idx = tid * 4 + it * 1024;
            *(float4*)&Wl[idx] = *(const float4*)&W[kc * 4096 + idx];
        }
        __syncthreads();
        const int kb = kc * 32;
#pragma unroll 2
        for (int ks = 0; ks < 32; ks += 4) {
            float4 xa[4];
#pragma unroll
            for (int i = 0; i < 4; ++i)
                xa[i] = *(const float4*)&tile[(ty * 4 + i) * TILE_LD + kb + ks];
#pragma unroll
            for (int kk = 0; kk < 4; ++kk) {
                float4 w0 = *(const float4*)&Wl[(ks + kk) * 128 + c0];
                float4 w1 = *(const float4*)&Wl[(ks + kk) * 128 + c0 + 64];
#pragma unroll
                for (int i = 0; i < 4; ++i) {
                    float a = (kk == 0) ? xa[i].x : (kk == 1) ? xa[i].y
                             : (kk == 2) ? xa[i].z : xa[i].w;
                    acc[0][i][0] = fmaf(a, w0.x, acc[0][i][0]);
                    acc[0][i][1] = fmaf(a, w0.y, acc[0][i][1]);
                    acc[0][i][2] = fmaf(a, w0.z, acc[0][i][2]);
                    acc[0][i][3] = fmaf(a, w0.w, acc[0][i][3]);
                    acc[1][i][0] = fmaf(a, w1.x, acc[1][i][0]);
                    acc[1][i][1] = fmaf(a, w1.y, acc[1][i][1]);
                    acc[1][i][2] = fmaf(a, w1.z, acc[1][i][2]);
                    acc[1][i][3] = fmaf(a, w1.w, acc[1][i][3]);
                }
            }
        }
    }
    float4 bb0 = *(const float4*)&bias[c0];
    float4 bb1 = *(const float4*)&bias[c0 + 64];
#pragma unroll
    for (int i = 0; i < 4; ++i) {
        int r = bid * 64 + ty * 4 + i;
        if (r < N_NODES) {
            float4 o0 = make_float4(acc[0][i][0] + bb0.x, acc[0][i][1] + bb0.y,
                                    acc[0][i][2] + bb0.z, acc[0][i][3] + bb0.w);
            float4 o1 = make_float4(acc[1][i][0] + bb1.x, acc[1][i][1] + bb1.y,
                                    acc[1][i][2] + bb1.z, acc[1][i][3] + bb1.w);
            if (ELU) {
                o0.x = o0.x > 0.f ? o0.x : expm1f(o0.x);
                o0.y = o0.y > 0.f ? o0.y : expm1f(o0.y);
                o0.z = o0.z > 0.f ? o0.z : expm1f(o0.z);
                o0.w = o0.w > 0.f ? o0.w : expm1f(o0.w);
                o1.x = o1.x > 0.f ? o1.x : expm1f(o1.x);
                o1.y = o1.y > 0.f ? o1.y : expm1f(o1.y);
                o1.z = o1.z > 0.f ? o1.z : expm1f(o1.z);
                o1.w = o1.w > 0.f ? o1.w : expm1f(o1.w);
            }
            float* p = Out + (size_t)r * 128 + c0;
            *(float4*)p = o0;
            *(float4*)(p + 64) = o1;
        }
    }

    // ---- phase 3 (layer 3 only): n_out = tile @ Wf + bf (tile untouched since barrier) ----
    if (PROJ) {
        if (tid < 128) {
            int nl = tid >> 1, c = tid & 1;
            int n = bid * 64 + nl;
            if (n < N_NODES) {
                float accp = bf[c];
#pragma unroll 8
                for (int k = 0; k < 128; k += 4) {
                    float4 g = *(const float4*)&tile[nl * TILE_LD + k];
                    accp += g.x * Wf[(k + 0) * 2 + c] + g.y * Wf[(k + 1) * 2 + c]
                          + g.z * Wf[(k + 2) * 2 + c] + g.w * Wf[(k + 3) * 2 + c];
                }
                proj_out[n * 2 + c] = accp;
            }
        }
    }
}

extern "C" void kernel_launch(void* const* d_in, const int* in_sizes, int n_in,
                              void* d_out, int out_size, void* d_ws, size_t ws_size,
                              hipStream_t stream) {
    const float* x     = (const float*)d_in[0];
    const int*   src   = (const int*)d_in[1];
    const int*   dst   = (const int*)d_in[2];
    const float* W1    = (const float*)d_in[3];
    const float* b1    = (const float*)d_in[4];
    const float* W2    = (const float*)d_in[5];
    const float* b2    = (const float*)d_in[6];
    const float* W3    = (const float*)d_in[7];
    const float* b3    = (const float*)d_in[8];
    const float* W_out = (const float*)d_in[9];
    const float* b_out = (const float*)d_in[10];

    float* out = (float*)d_out;                 // n_out: N*2, then n_embed: N*128
    float* emb = out + (size_t)N_NODES * 2;

    char* ws = (char*)d_ws;
    float* norm_src  = (float*)(ws + 0);             // 200192
    float* norm_dst  = (float*)(ws + 200192);        // 200192
    int*   deg_in    = (int*)(ws + 400384);          // 200192
    int*   row_start = (int*)(ws + 600576);          // 200704 (N+1 ints)
    int*   cursor    = (int*)(ws + 801280);          // 200192
    int*   partials98= (int*)(ws + 1001472);         // 512
    float* Wf        = (float*)(ws + 1001984);       // 1024 (128x2)
    float* bf        = (float*)(ws + 1003008);       // 512 (2 used)
    int2*  csr       = (int2*)(ws + 1003520);        // 6,400,000
    float* bufA      = (float*)(ws + 7403520);       // 25,600,000 (h1)
    float* bufB      = (float*)(ws + 33003520);      // 25,600,000 (m1, then h2) end 58.6MB
    // partO/partI (12.8 MB each) alias bufA exactly; dead before gather1 writes bufA.
    unsigned int* partO = (unsigned int*)bufA;
    unsigned int* partI = partO + (size_t)NB_HIST * WORDS;

    const int gridW = (N_NODES * 64 + 255) / 256;      // 12500 (wave per node)
    const int gridF = GRID_G + (N_EDGES + 255) / 256;  // gemm + fill blocks

    k_wfuse<<<1, 256, 0, stream>>>(W3, W_out, b3, b_out, Wf, bf);
    k_hist<<<NB_HIST, 256, 0, stream>>>(src, dst, partO, partI);
    k_normB<<<NORMB_BLOCKS, 256, 0, stream>>>(partO, partI, norm_src, norm_dst,
                                              deg_in, partials98);
    k_scan<<<NORMB_BLOCKS, 256, 0, stream>>>(deg_in, partials98, row_start, cursor);
    // layer 1: GEMM1 (x@W1) fused with CSR fill, then gather (+b1, ELU) -> h1
    k_gemm_fill<<<gridF, 256, 0, stream>>>(x, W1, bufB, src, dst, norm_src,
                                           cursor, csr);
    k_gather<<<gridW, 256, 0, stream>>>(bufB, row_start, csr, norm_dst, b1, bufA);
    // layer 2: fused gather(h1) @ W2 + b2, ELU -> h2
    k_fused<1, 0><<<GRID_G, 256, 0, stream>>>(bufA, row_start, csr, norm_dst,
                                              W2, b2, bufB, nullptr, nullptr, nullptr);
    // layer 3: fused gather(h2) @ W3 + b3 -> emb, plus n_out = tile @ Wf + bf
    k_fused<0, 1><<<GRID_G, 256, 0, stream>>>(bufB, row_start, csr, norm_dst,
                                              W3, b3, emb, Wf, bf, out);
}

// Round 13
// 329.234 us; speedup vs baseline: 1.2570x; 1.2570x over previous
//
#include <hip/hip_runtime.h>

#define N_NODES 50000
#define N_EDGES 800000
#define GRID_G 782        // ceil(N_NODES/64) gemm blocks (64 rows/block; round-8 best)
#define NB_HIST 128       // histogram blocks
#define EPB (N_EDGES / NB_HIST)   // 6250 edges per hist block
#define WORDS 25000       // N_NODES/2 packed 2x16 words
#define NORMB_BLOCKS 98   // ceil(WORDS/256); each covers 512 nodes

// ---------------- histogram degree count (no global atomics) ----------------
__global__ __launch_bounds__(256) void k_hist(const int* __restrict__ src,
                                              const int* __restrict__ dst,
                                              unsigned int* __restrict__ partO,
                                              unsigned int* __restrict__ partI) {
    __shared__ unsigned int h[12500];   // 50 KB: 25000 nodes packed 2 per word
    const int e0 = blockIdx.x * EPB;
    for (int kind = 0; kind < 2; ++kind) {
        const int* ids = kind ? dst : src;
        unsigned int* out = kind ? partI : partO;
        for (int p = 0; p < 2; ++p) {
            for (int i = threadIdx.x; i < 12500; i += 256) h[i] = 0;
            __syncthreads();
            const int base = p * 25000;
            for (int i = threadIdx.x; i < EPB; i += 256) {
                int id = ids[e0 + i] - base;
                if ((unsigned)id < 25000u)
                    atomicAdd(&h[id >> 1], (id & 1) ? 0x10000u : 1u);
            }
            __syncthreads();
            unsigned int* o = out + blockIdx.x * WORDS + p * 12500;
            for (int i = threadIdx.x; i < 12500; i += 256) o[i] = h[i];
            __syncthreads();
        }
    }
}

// ---------------- reduce partials -> degrees, norms, scan block-sums ----------------
__global__ __launch_bounds__(256) void k_normB(const unsigned int* __restrict__ partO,
                                               const unsigned int* __restrict__ partI,
                                               float* __restrict__ norm_src,
                                               float* __restrict__ norm_dst,
                                               int* __restrict__ deg_in,
                                               int* __restrict__ partials98) {
    __shared__ int sm4[4];
    int w = blockIdx.x * 256 + threadIdx.x;
    unsigned int lo_o = 0, hi_o = 0, lo_i = 0, hi_i = 0;
    if (w < WORDS) {
        for (int b = 0; b < NB_HIST; ++b) {
            unsigned int vo = partO[b * WORDS + w];
            unsigned int vi = partI[b * WORDS + w];
            lo_o += vo & 0xFFFFu; hi_o += vo >> 16;
            lo_i += vi & 0xFFFFu; hi_i += vi >> 16;
        }
        int n0 = 2 * w;
        *(float2*)&norm_src[n0] = make_float2(rsqrtf((float)max(lo_o, 1u)),
                                              rsqrtf((float)max(hi_o, 1u)));
        *(float2*)&norm_dst[n0] = make_float2(rsqrtf((float)max(lo_i, 1u)),
                                              rsqrtf((float)max(hi_i, 1u)));
        *(int2*)&deg_in[n0] = make_int2((int)lo_i, (int)hi_i);
    }
    int v = (int)(lo_i + hi_i);
#pragma unroll
    for (int off = 32; off > 0; off >>= 1) v += __shfl_down(v, off);
    int lane = threadIdx.x & 63, wv = threadIdx.x >> 6;
    if (lane == 0) sm4[wv] = v;
    __syncthreads();
    if (threadIdx.x == 0)
        partials98[blockIdx.x] = sm4[0] + sm4[1] + sm4[2] + sm4[3];
}

// ---------------- scan: exclusive prefix over deg_in (512 nodes/block) ----------------
__global__ __launch_bounds__(256) void k_scan(const int* __restrict__ deg_in,
                                              const int* __restrict__ partials98,
                                              int* __restrict__ row_start,
                                              int* __restrict__ cursor) {
    __shared__ int sm[256];
    __shared__ int carry_s;
    int t = threadIdx.x;
    if (t < 64) {
        int acc = 0;
        for (int i = t; i < blockIdx.x; i += 64) acc += partials98[i];
#pragma unroll
        for (int off = 32; off > 0; off >>= 1) acc += __shfl_down(acc, off);
        if (t == 0) carry_s = acc;
    }
    int n0 = blockIdx.x * 512 + t * 2;
    int a0 = 0, a1 = 0;
    if (n0 + 1 < N_NODES) {
        int2 d = *(const int2*)&deg_in[n0];
        a0 = d.x; a1 = d.y;
    } else if (n0 < N_NODES) {
        a0 = deg_in[n0];
    }
    sm[t] = a0 + a1;
    __syncthreads();
#pragma unroll
    for (int off = 1; off < 256; off <<= 1) {
        int tv = (t >= off) ? sm[t - off] : 0;
        __syncthreads();
        sm[t] += tv;
        __syncthreads();
    }
    int excl = sm[t] - (a0 + a1) + carry_s;
    if (n0 < N_NODES) { row_start[n0] = excl; cursor[n0] = excl; }
    if (n0 + 1 < N_NODES) { row_start[n0 + 1] = excl + a0; cursor[n0 + 1] = excl + a0; }
    if (blockIdx.x == 0 && t == 0) row_start[N_NODES] = N_EDGES;
}

// ---------------- GEMM body: G = X @ W (N,128)x(128,128) ----------------
// Round-8 geometry (best measured): 64 rows/block; thread (ty,tx): 4 rows x 8 cols
// (c0/c0+64 split, conflict-free). W staged in two 32 KB chunks.
// NEW vs round 8: X register prefetch deepened to 2 steps (xa/xb/xc rotation) --
// grid caps us at 3 blocks/CU so occupancy can't rise; extra per-wave MLP is the
// only remaining latency lever and extra VGPR is free under the (256,4)=128 cap.
// (Round 7: (256,8) cap-64 spilled. Round 4: full unroll spilled. Watch WRITE_SIZE.)
__device__ __forceinline__ void gemm_body(const float* __restrict__ X,
                                          const float* __restrict__ W,
                                          float* __restrict__ G,
                                          float* __restrict__ Wl, int bid) {
    const int tx = threadIdx.x & 15;
    const int ty = threadIdx.x >> 4;
    const int r0 = bid * 64 + ty * 4;
    const int c0 = tx * 4;

    const float* xr[4];
#pragma unroll
    for (int i = 0; i < 4; ++i) {
        int r = r0 + i; if (r > N_NODES - 1) r = N_NODES - 1;
        xr[i] = X + (size_t)r * 128;
    }

    float acc[2][4][4] = {};
    float4 xa[4], xb[4], xc[4];
#pragma unroll
    for (int i = 0; i < 4; ++i) {
        xa[i] = *(const float4*)(xr[i]);
        xb[i] = *(const float4*)(xr[i] + 4);
    }

    for (int kc = 0; kc < 2; ++kc) {
        __syncthreads();
#pragma unroll
        for (int it = 0; it < 8; ++it) {
            int idx = threadIdx.x * 4 + it * 1024;
            *(float4*)&Wl[idx] = *(const float4*)&W[kc * 8192 + idx];
        }
        __syncthreads();
        const int kb = kc * 64;
#pragma unroll 2
        for (int ks = 0; ks < 64; ks += 4) {
            int kn = kb + ks + 8;                 // 2-deep prefetch (crosses chunks)
            if (kn > 124) kn = 124;               // tail re-reads (L1 hit)
#pragma unroll
            for (int i = 0; i < 4; ++i) xc[i] = *(const float4*)(xr[i] + kn);
#pragma unroll
            for (int kk = 0; kk < 4; ++kk) {
                float4 w0 = *(const float4*)&Wl[(ks + kk) * 128 + c0];
                float4 w1 = *(const float4*)&Wl[(ks + kk) * 128 + c0 + 64];
#pragma unroll
                for (int i = 0; i < 4; ++i) {
                    float a = (kk == 0) ? xa[i].x : (kk == 1) ? xa[i].y
                             : (kk == 2) ? xa[i].z : xa[i].w;
                    acc[0][i][0] = fmaf(a, w0.x, acc[0][i][0]);
                    acc[0][i][1] = fmaf(a, w0.y, acc[0][i][1]);
                    acc[0][i][2] = fmaf(a, w0.z, acc[0][i][2]);
                    acc[0][i][3] = fmaf(a, w0.w, acc[0][i][3]);
                    acc[1][i][0] = fmaf(a, w1.x, acc[1][i][0]);
                    acc[1][i][1] = fmaf(a, w1.y, acc[1][i][1]);
                    acc[1][i][2] = fmaf(a, w1.z, acc[1][i][2]);
                    acc[1][i][3] = fmaf(a, w1.w, acc[1][i][3]);
                }
            }
#pragma unroll
            for (int i = 0; i < 4; ++i) { xa[i] = xb[i]; xb[i] = xc[i]; }
        }
    }
#pragma unroll
    for (int i = 0; i < 4; ++i) {
        int r = r0 + i;
        if (r < N_NODES) {
            float* p = G + (size_t)r * 128 + c0;
            *(float4*)p = make_float4(acc[0][i][0], acc[0][i][1], acc[0][i][2], acc[0][i][3]);
            *(float4*)(p + 64) = make_float4(acc[1][i][0], acc[1][i][1], acc[1][i][2], acc[1][i][3]);
        }
    }
}

__global__ __launch_bounds__(256, 4) void k_gemm(const float* __restrict__ X,
                                                 const float* __restrict__ W,
                                                 float* __restrict__ G) {
    __shared__ float Wl[8192];
    gemm_body(X, W, G, Wl, blockIdx.x);
}

// ---------------- fused: GEMM1 (graph-independent) + CSR fill ----------------
__global__ __launch_bounds__(256, 4) void k_gemm_fill(const float* __restrict__ X,
                                                      const float* __restrict__ W,
                                                      float* __restrict__ G,
                                                      const int* __restrict__ src,
                                                      const int* __restrict__ dst,
                                                      const float* __restrict__ norm_src,
                                                      int* __restrict__ cursor,
                                                      int2* __restrict__ csr) {
    __shared__ float Wl[8192];
    if (blockIdx.x < GRID_G) {
        gemm_body(X, W, G, Wl, blockIdx.x);
    } else {
        int e = (blockIdx.x - GRID_G) * 256 + threadIdx.x;
        if (e < N_EDGES) {
            int d = dst[e], s = src[e];
            int pos = atomicAdd(&cursor[d], 1);
            csr[pos] = make_int2(s, __float_as_int(norm_src[s]));
        }
    }
}

// ---------------- gather: Out[n] = act(norm_dst[n] * sum_e w_e * G[src_e] + b) ----------------
// Round-8 form (best measured): one wave per node, edge-pair scheme (lanes 0-31 even
// edges, 32-63 odd, float4 cols l*4..l*4+3, shfl_xor(32) combine), 8-wide loop.
template <int ELU, int PROJ>
__global__ __launch_bounds__(256) void k_gather(const float* __restrict__ G,
                                                const int* __restrict__ row_start,
                                                const int2* __restrict__ csr,
                                                const float* __restrict__ norm_dst,
                                                const float* __restrict__ bias,
                                                float* __restrict__ Out,
                                                const float* __restrict__ Wo,
                                                const float* __restrict__ bo,
                                                float* __restrict__ proj_out) {
    int n = (blockIdx.x * 256 + threadIdx.x) >> 6;
    int lane = threadIdx.x & 63;
    if (n >= N_NODES) return;
    const int half = lane >> 5;
    const int l = lane & 31;
    int e0 = row_start[n], e1 = row_start[n + 1];
    float4 a0 = {0,0,0,0}, a1 = {0,0,0,0}, a2 = {0,0,0,0}, a3 = {0,0,0,0};
    int e = e0;
    for (; e + 8 <= e1; e += 8) {
        int2 c0 = csr[e + half],     c1 = csr[e + 2 + half];
        int2 c2 = csr[e + 4 + half], c3 = csr[e + 6 + half];
        float4 g0 = *(const float4*)(G + (size_t)c0.x * 128 + l * 4);
        float4 g1 = *(const float4*)(G + (size_t)c1.x * 128 + l * 4);
        float4 g2 = *(const float4*)(G + (size_t)c2.x * 128 + l * 4);
        float4 g3 = *(const float4*)(G + (size_t)c3.x * 128 + l * 4);
        float w0 = __int_as_float(c0.y), w1 = __int_as_float(c1.y);
        float w2 = __int_as_float(c2.y), w3 = __int_as_float(c3.y);
        a0.x = fmaf(w0, g0.x, a0.x); a0.y = fmaf(w0, g0.y, a0.y);
        a0.z = fmaf(w0, g0.z, a0.z); a0.w = fmaf(w0, g0.w, a0.w);
        a1.x = fmaf(w1, g1.x, a1.x); a1.y = fmaf(w1, g1.y, a1.y);
        a1.z = fmaf(w1, g1.z, a1.z); a1.w = fmaf(w1, g1.w, a1.w);
        a2.x = fmaf(w2, g2.x, a2.x); a2.y = fmaf(w2, g2.y, a2.y);
        a2.z = fmaf(w2, g2.z, a2.z); a2.w = fmaf(w2, g2.w, a2.w);
        a3.x = fmaf(w3, g3.x, a3.x); a3.y = fmaf(w3, g3.y, a3.y);
        a3.z = fmaf(w3, g3.z, a3.z); a3.w = fmaf(w3, g3.w, a3.w);
    }
    for (; e < e1; e += 2) {
        int idx = e + half;
        if (idx < e1) {
            int2 c = csr[idx];
            float w = __int_as_float(c.y);
            float4 g = *(const float4*)(G + (size_t)c.x * 128 + l * 4);
            a0.x = fmaf(w, g.x, a0.x); a0.y = fmaf(w, g.y, a0.y);
            a0.z = fmaf(w, g.z, a0.z); a0.w = fmaf(w, g.w, a0.w);
        }
    }
    float4 s;
    s.x = (a0.x + a1.x) + (a2.x + a3.x);
    s.y = (a0.y + a1.y) + (a2.y + a3.y);
    s.z = (a0.z + a1.z) + (a2.z + a3.z);
    s.w = (a0.w + a1.w) + (a2.w + a3.w);
    s.x += __shfl_xor(s.x, 32);
    s.y += __shfl_xor(s.y, 32);
    s.z += __shfl_xor(s.z, 32);
    s.w += __shfl_xor(s.w, 32);
    float nd = norm_dst[n];
    float4 b = *(const float4*)(bias + l * 4);
    float4 o;
    o.x = fmaf(nd, s.x, b.x);
    o.y = fmaf(nd, s.y, b.y);
    o.z = fmaf(nd, s.z, b.z);
    o.w = fmaf(nd, s.w, b.w);
    if (ELU) {
        o.x = o.x > 0.f ? o.x : expm1f(o.x);
        o.y = o.y > 0.f ? o.y : expm1f(o.y);
        o.z = o.z > 0.f ? o.z : expm1f(o.z);
        o.w = o.w > 0.f ? o.w : expm1f(o.w);
    }
    if (half == 0)
        *(float4*)(Out + (size_t)n * 128 + l * 4) = o;
    if (PROJ) {
        float p0 = o.x * Wo[(l * 4 + 0) * 2] + o.y * Wo[(l * 4 + 1) * 2]
                 + o.z * Wo[(l * 4 + 2) * 2] + o.w * Wo[(l * 4 + 3) * 2];
        float p1 = o.x * Wo[(l * 4 + 0) * 2 + 1] + o.y * Wo[(l * 4 + 1) * 2 + 1]
                 + o.z * Wo[(l * 4 + 2) * 2 + 1] + o.w * Wo[(l * 4 + 3) * 2 + 1];
#pragma unroll
        for (int off = 16; off > 0; off >>= 1) {
            p0 += __shfl_down(p0, off);
            p1 += __shfl_down(p1, off);
        }
        if (lane == 0) {
            proj_out[n * 2 + 0] = p0 + bo[0];
            proj_out[n * 2 + 1] = p1 + bo[1];
        }
    }
}

extern "C" void kernel_launch(void* const* d_in, const int* in_sizes, int n_in,
                              void* d_out, int out_size, void* d_ws, size_t ws_size,
                              hipStream_t stream) {
    const float* x     = (const float*)d_in[0];
    const int*   src   = (const int*)d_in[1];
    const int*   dst   = (const int*)d_in[2];
    const float* W1    = (const float*)d_in[3];
    const float* b1    = (const float*)d_in[4];
    const float* W2    = (const float*)d_in[5];
    const float* b2    = (const float*)d_in[6];
    const float* W3    = (const float*)d_in[7];
    const float* b3    = (const float*)d_in[8];
    const float* W_out = (const float*)d_in[9];
    const float* b_out = (const float*)d_in[10];

    float* out = (float*)d_out;                 // n_out: N*2, then n_embed: N*128
    float* emb = out + (size_t)N_NODES * 2;

    char* ws = (char*)d_ws;
    float* norm_src  = (float*)(ws + 0);             // 200192
    float* norm_dst  = (float*)(ws + 200192);        // 200192
    int*   deg_in    = (int*)(ws + 400384);          // 200192
    int*   row_start = (int*)(ws + 600576);          // 200704 (N+1 ints)
    int*   cursor    = (int*)(ws + 801280);          // 200192
    int*   partials98= (int*)(ws + 1001472);         // 512
    int2*  csr       = (int2*)(ws + 1001984);        // 6,400,000
    float* bufA      = (float*)(ws + 7401984);       // 25,600,000
    float* bufB      = (float*)(ws + 33001984);      // 25,600,000  (end 58.6 MB)
    // partO/partI (12.8 MB each) alias bufA exactly; dead before gather1 writes bufA.
    unsigned int* partO = (unsigned int*)bufA;
    unsigned int* partI = partO + (size_t)NB_HIST * WORDS;

    const int gridW = (N_NODES * 64 + 255) / 256;      // 12500 (wave per node)
    const int gridF = GRID_G + (N_EDGES + 255) / 256;  // gemm + fill blocks

    k_hist<<<NB_HIST, 256, 0, stream>>>(src, dst, partO, partI);
    k_normB<<<NORMB_BLOCKS, 256, 0, stream>>>(partO, partI, norm_src, norm_dst,
                                              deg_in, partials98);
    k_scan<<<NORMB_BLOCKS, 256, 0, stream>>>(deg_in, partials98, row_start, cursor);
    // GEMM1 (x@W1, graph-independent) fused with CSR fill
    k_gemm_fill<<<gridF, 256, 0, stream>>>(x, W1, bufB, src, dst, norm_src,
                                           cursor, csr);
    k_gather<1, 0><<<gridW, 256, 0, stream>>>(bufB, row_start, csr, norm_dst, b1,
                                              bufA, nullptr, nullptr, nullptr);
    k_gemm<<<GRID_G, 256, 0, stream>>>(bufA, W2, bufB);
    k_gather<1, 0><<<gridW, 256, 0, stream>>>(bufB, row_start, csr, norm_dst, b2,
                                              bufA, nullptr, nullptr, nullptr);
    k_gemm<<<GRID_G, 256, 0, stream>>>(bufA, W3, bufB);
    k_gather<0, 1><<<gridW, 256, 0, stream>>>(bufB, row_start, csr, norm_dst, b3,
                                              emb, W_out, b_out, out);
}

// Round 14
// 325.509 us; speedup vs baseline: 1.2713x; 1.0114x over previous
//
#include <hip/hip_runtime.h>

#define N_NODES 50000
#define N_EDGES 800000
#define GRID_G 782        // ceil(N_NODES/64) gemm blocks (64 rows/block; round-8 best)
#define NB_HIST 128       // histogram blocks
#define EPB (N_EDGES / NB_HIST)   // 6250 edges per hist block
#define WORDS 25000       // N_NODES/2 packed 2x16 words
#define NORMB_BLOCKS 98   // ceil(WORDS/256); each covers 512 nodes

// ---------------- histogram degree count (no global atomics) ----------------
__global__ __launch_bounds__(256) void k_hist(const int* __restrict__ src,
                                              const int* __restrict__ dst,
                                              unsigned int* __restrict__ partO,
                                              unsigned int* __restrict__ partI) {
    __shared__ unsigned int h[12500];   // 50 KB: 25000 nodes packed 2 per word
    const int e0 = blockIdx.x * EPB;
    for (int kind = 0; kind < 2; ++kind) {
        const int* ids = kind ? dst : src;
        unsigned int* out = kind ? partI : partO;
        for (int p = 0; p < 2; ++p) {
            for (int i = threadIdx.x; i < 12500; i += 256) h[i] = 0;
            __syncthreads();
            const int base = p * 25000;
            for (int i = threadIdx.x; i < EPB; i += 256) {
                int id = ids[e0 + i] - base;
                if ((unsigned)id < 25000u)
                    atomicAdd(&h[id >> 1], (id & 1) ? 0x10000u : 1u);
            }
            __syncthreads();
            unsigned int* o = out + blockIdx.x * WORDS + p * 12500;
            for (int i = threadIdx.x; i < 12500; i += 256) o[i] = h[i];
            __syncthreads();
        }
    }
}

// ---------------- reduce partials -> degrees, norms, scan block-sums ----------------
__global__ __launch_bounds__(256) void k_normB(const unsigned int* __restrict__ partO,
                                               const unsigned int* __restrict__ partI,
                                               float* __restrict__ norm_src,
                                               float* __restrict__ norm_dst,
                                               int* __restrict__ deg_in,
                                               int* __restrict__ partials98) {
    __shared__ int sm4[4];
    int w = blockIdx.x * 256 + threadIdx.x;
    unsigned int lo_o = 0, hi_o = 0, lo_i = 0, hi_i = 0;
    if (w < WORDS) {
        for (int b = 0; b < NB_HIST; ++b) {
            unsigned int vo = partO[b * WORDS + w];
            unsigned int vi = partI[b * WORDS + w];
            lo_o += vo & 0xFFFFu; hi_o += vo >> 16;
            lo_i += vi & 0xFFFFu; hi_i += vi >> 16;
        }
        int n0 = 2 * w;
        *(float2*)&norm_src[n0] = make_float2(rsqrtf((float)max(lo_o, 1u)),
                                              rsqrtf((float)max(hi_o, 1u)));
        *(float2*)&norm_dst[n0] = make_float2(rsqrtf((float)max(lo_i, 1u)),
                                              rsqrtf((float)max(hi_i, 1u)));
        *(int2*)&deg_in[n0] = make_int2((int)lo_i, (int)hi_i);
    }
    int v = (int)(lo_i + hi_i);
#pragma unroll
    for (int off = 32; off > 0; off >>= 1) v += __shfl_down(v, off);
    int lane = threadIdx.x & 63, wv = threadIdx.x >> 6;
    if (lane == 0) sm4[wv] = v;
    __syncthreads();
    if (threadIdx.x == 0)
        partials98[blockIdx.x] = sm4[0] + sm4[1] + sm4[2] + sm4[3];
}

// ---------------- scan: exclusive prefix over deg_in (512 nodes/block) ----------------
__global__ __launch_bounds__(256) void k_scan(const int* __restrict__ deg_in,
                                              const int* __restrict__ partials98,
                                              int* __restrict__ row_start,
                                              int* __restrict__ cursor) {
    __shared__ int sm[256];
    __shared__ int carry_s;
    int t = threadIdx.x;
    if (t < 64) {
        int acc = 0;
        for (int i = t; i < blockIdx.x; i += 64) acc += partials98[i];
#pragma unroll
        for (int off = 32; off > 0; off >>= 1) acc += __shfl_down(acc, off);
        if (t == 0) carry_s = acc;
    }
    int n0 = blockIdx.x * 512 + t * 2;
    int a0 = 0, a1 = 0;
    if (n0 + 1 < N_NODES) {
        int2 d = *(const int2*)&deg_in[n0];
        a0 = d.x; a1 = d.y;
    } else if (n0 < N_NODES) {
        a0 = deg_in[n0];
    }
    sm[t] = a0 + a1;
    __syncthreads();
#pragma unroll
    for (int off = 1; off < 256; off <<= 1) {
        int tv = (t >= off) ? sm[t - off] : 0;
        __syncthreads();
        sm[t] += tv;
        __syncthreads();
    }
    int excl = sm[t] - (a0 + a1) + carry_s;
    if (n0 < N_NODES) { row_start[n0] = excl; cursor[n0] = excl; }
    if (n0 + 1 < N_NODES) { row_start[n0 + 1] = excl + a0; cursor[n0 + 1] = excl + a0; }
    if (blockIdx.x == 0 && t == 0) row_start[N_NODES] = N_EDGES;
}

// ---------------- GEMM body: G = X @ W (N,128)x(128,128) ----------------
// Round-8 tile (64 rows/block, thread 4x8, c0/c0+64 split) but X batched in 16-k
// chunks: float4 xa[4][4] (64 VGPR, STATIC indices) forces 16 global loads in
// flight before each 512-FMA block -- round 13 showed a source-level rotation
// gets collapsed by the allocator (VGPR stayed 64); a static array is binding.
// Budget: acc 32 + xa 64 + addr ~ 110 < 128 cap from (256,4). Spill tripwire:
// VGPR=128 + WRITE_SIZE blowup => revert (round-4/7 lessons).
__device__ __forceinline__ void gemm_body(const float* __restrict__ X,
                                          const float* __restrict__ W,
                                          float* __restrict__ G,
                                          float* __restrict__ Wl, int bid) {
    const int tx = threadIdx.x & 15;
    const int ty = threadIdx.x >> 4;
    const int r0 = bid * 64 + ty * 4;
    const int c0 = tx * 4;

    const float* xr[4];
#pragma unroll
    for (int i = 0; i < 4; ++i) {
        int r = r0 + i; if (r > N_NODES - 1) r = N_NODES - 1;
        xr[i] = X + (size_t)r * 128;
    }

    float acc[2][4][4] = {};
    for (int kc = 0; kc < 2; ++kc) {
        __syncthreads();
#pragma unroll
        for (int it = 0; it < 8; ++it) {
            int idx = threadIdx.x * 4 + it * 1024;
            *(float4*)&Wl[idx] = *(const float4*)&W[kc * 8192 + idx];
        }
        __syncthreads();
        const int kb = kc * 64;
#pragma unroll
        for (int kq = 0; kq < 4; ++kq) {          // 16-k batches
            float4 xa[4][4];                      // static-indexed: stays in VGPRs
#pragma unroll
            for (int j = 0; j < 4; ++j)
#pragma unroll
                for (int i = 0; i < 4; ++i)
                    xa[i][j] = *(const float4*)(xr[i] + kb + kq * 16 + j * 4);
#pragma unroll
            for (int j = 0; j < 4; ++j) {
                const int ks = kq * 16 + j * 4;
#pragma unroll
                for (int kk = 0; kk < 4; ++kk) {
                    float4 w0 = *(const float4*)&Wl[(ks + kk) * 128 + c0];
                    float4 w1 = *(const float4*)&Wl[(ks + kk) * 128 + c0 + 64];
#pragma unroll
                    for (int i = 0; i < 4; ++i) {
                        float a = (kk == 0) ? xa[i][j].x : (kk == 1) ? xa[i][j].y
                                 : (kk == 2) ? xa[i][j].z : xa[i][j].w;
                        acc[0][i][0] = fmaf(a, w0.x, acc[0][i][0]);
                        acc[0][i][1] = fmaf(a, w0.y, acc[0][i][1]);
                        acc[0][i][2] = fmaf(a, w0.z, acc[0][i][2]);
                        acc[0][i][3] = fmaf(a, w0.w, acc[0][i][3]);
                        acc[1][i][0] = fmaf(a, w1.x, acc[1][i][0]);
                        acc[1][i][1] = fmaf(a, w1.y, acc[1][i][1]);
                        acc[1][i][2] = fmaf(a, w1.z, acc[1][i][2]);
                        acc[1][i][3] = fmaf(a, w1.w, acc[1][i][3]);
                    }
                }
            }
        }
    }
#pragma unroll
    for (int i = 0; i < 4; ++i) {
        int r = r0 + i;
        if (r < N_NODES) {
            float* p = G + (size_t)r * 128 + c0;
            *(float4*)p = make_float4(acc[0][i][0], acc[0][i][1], acc[0][i][2], acc[0][i][3]);
            *(float4*)(p + 64) = make_float4(acc[1][i][0], acc[1][i][1], acc[1][i][2], acc[1][i][3]);
        }
    }
}

__global__ __launch_bounds__(256, 4) void k_gemm(const float* __restrict__ X,
                                                 const float* __restrict__ W,
                                                 float* __restrict__ G) {
    __shared__ float Wl[8192];
    gemm_body(X, W, G, Wl, blockIdx.x);
}

// ---------------- fused: GEMM1 (graph-independent) + CSR fill ----------------
__global__ __launch_bounds__(256, 4) void k_gemm_fill(const float* __restrict__ X,
                                                      const float* __restrict__ W,
                                                      float* __restrict__ G,
                                                      const int* __restrict__ src,
                                                      const int* __restrict__ dst,
                                                      const float* __restrict__ norm_src,
                                                      int* __restrict__ cursor,
                                                      int2* __restrict__ csr) {
    __shared__ float Wl[8192];
    if (blockIdx.x < GRID_G) {
        gemm_body(X, W, G, Wl, blockIdx.x);
    } else {
        int e = (blockIdx.x - GRID_G) * 256 + threadIdx.x;
        if (e < N_EDGES) {
            int d = dst[e], s = src[e];
            int pos = atomicAdd(&cursor[d], 1);
            csr[pos] = make_int2(s, __float_as_int(norm_src[s]));
        }
    }
}

// ---------------- gather: Out[n] = act(norm_dst[n] * sum_e w_e * G[src_e] + b) ----------------
// Round-8 form (best measured): one wave per node, edge-pair scheme (lanes 0-31 even
// edges, 32-63 odd, float4 cols l*4..l*4+3, shfl_xor(32) combine), 8-wide loop.
template <int ELU, int PROJ>
__global__ __launch_bounds__(256) void k_gather(const float* __restrict__ G,
                                                const int* __restrict__ row_start,
                                                const int2* __restrict__ csr,
                                                const float* __restrict__ norm_dst,
                                                const float* __restrict__ bias,
                                                float* __restrict__ Out,
                                                const float* __restrict__ Wo,
                                                const float* __restrict__ bo,
                                                float* __restrict__ proj_out) {
    int n = (blockIdx.x * 256 + threadIdx.x) >> 6;
    int lane = threadIdx.x & 63;
    if (n >= N_NODES) return;
    const int half = lane >> 5;
    const int l = lane & 31;
    int e0 = row_start[n], e1 = row_start[n + 1];
    float4 a0 = {0,0,0,0}, a1 = {0,0,0,0}, a2 = {0,0,0,0}, a3 = {0,0,0,0};
    int e = e0;
    for (; e + 8 <= e1; e += 8) {
        int2 c0 = csr[e + half],     c1 = csr[e + 2 + half];
        int2 c2 = csr[e + 4 + half], c3 = csr[e + 6 + half];
        float4 g0 = *(const float4*)(G + (size_t)c0.x * 128 + l * 4);
        float4 g1 = *(const float4*)(G + (size_t)c1.x * 128 + l * 4);
        float4 g2 = *(const float4*)(G + (size_t)c2.x * 128 + l * 4);
        float4 g3 = *(const float4*)(G + (size_t)c3.x * 128 + l * 4);
        float w0 = __int_as_float(c0.y), w1 = __int_as_float(c1.y);
        float w2 = __int_as_float(c2.y), w3 = __int_as_float(c3.y);
        a0.x = fmaf(w0, g0.x, a0.x); a0.y = fmaf(w0, g0.y, a0.y);
        a0.z = fmaf(w0, g0.z, a0.z); a0.w = fmaf(w0, g0.w, a0.w);
        a1.x = fmaf(w1, g1.x, a1.x); a1.y = fmaf(w1, g1.y, a1.y);
        a1.z = fmaf(w1, g1.z, a1.z); a1.w = fmaf(w1, g1.w, a1.w);
        a2.x = fmaf(w2, g2.x, a2.x); a2.y = fmaf(w2, g2.y, a2.y);
        a2.z = fmaf(w2, g2.z, a2.z); a2.w = fmaf(w2, g2.w, a2.w);
        a3.x = fmaf(w3, g3.x, a3.x); a3.y = fmaf(w3, g3.y, a3.y);
        a3.z = fmaf(w3, g3.z, a3.z); a3.w = fmaf(w3, g3.w, a3.w);
    }
    for (; e < e1; e += 2) {
        int idx = e + half;
        if (idx < e1) {
            int2 c = csr[idx];
            float w = __int_as_float(c.y);
            float4 g = *(const float4*)(G + (size_t)c.x * 128 + l * 4);
            a0.x = fmaf(w, g.x, a0.x); a0.y = fmaf(w, g.y, a0.y);
            a0.z = fmaf(w, g.z, a0.z); a0.w = fmaf(w, g.w, a0.w);
        }
    }
    float4 s;
    s.x = (a0.x + a1.x) + (a2.x + a3.x);
    s.y = (a0.y + a1.y) + (a2.y + a3.y);
    s.z = (a0.z + a1.z) + (a2.z + a3.z);
    s.w = (a0.w + a1.w) + (a2.w + a3.w);
    s.x += __shfl_xor(s.x, 32);
    s.y += __shfl_xor(s.y, 32);
    s.z += __shfl_xor(s.z, 32);
    s.w += __shfl_xor(s.w, 32);
    float nd = norm_dst[n];
    float4 b = *(const float4*)(bias + l * 4);
    float4 o;
    o.x = fmaf(nd, s.x, b.x);
    o.y = fmaf(nd, s.y, b.y);
    o.z = fmaf(nd, s.z, b.z);
    o.w = fmaf(nd, s.w, b.w);
    if (ELU) {
        o.x = o.x > 0.f ? o.x : expm1f(o.x);
        o.y = o.y > 0.f ? o.y : expm1f(o.y);
        o.z = o.z > 0.f ? o.z : expm1f(o.z);
        o.w = o.w > 0.f ? o.w : expm1f(o.w);
    }
    if (half == 0)
        *(float4*)(Out + (size_t)n * 128 + l * 4) = o;
    if (PROJ) {
        float p0 = o.x * Wo[(l * 4 + 0) * 2] + o.y * Wo[(l * 4 + 1) * 2]
                 + o.z * Wo[(l * 4 + 2) * 2] + o.w * Wo[(l * 4 + 3) * 2];
        float p1 = o.x * Wo[(l * 4 + 0) * 2 + 1] + o.y * Wo[(l * 4 + 1) * 2 + 1]
                 + o.z * Wo[(l * 4 + 2) * 2 + 1] + o.w * Wo[(l * 4 + 3) * 2 + 1];
#pragma unroll
        for (int off = 16; off > 0; off >>= 1) {
            p0 += __shfl_down(p0, off);
            p1 += __shfl_down(p1, off);
        }
        if (lane == 0) {
            proj_out[n * 2 + 0] = p0 + bo[0];
            proj_out[n * 2 + 1] = p1 + bo[1];
        }
    }
}

extern "C" void kernel_launch(void* const* d_in, const int* in_sizes, int n_in,
                              void* d_out, int out_size, void* d_ws, size_t ws_size,
                              hipStream_t stream) {
    const float* x     = (const float*)d_in[0];
    const int*   src   = (const int*)d_in[1];
    const int*   dst   = (const int*)d_in[2];
    const float* W1    = (const float*)d_in[3];
    const float* b1    = (const float*)d_in[4];
    const float* W2    = (const float*)d_in[5];
    const float* b2    = (const float*)d_in[6];
    const float* W3    = (const float*)d_in[7];
    const float* b3    = (const float*)d_in[8];
    const float* W_out = (const float*)d_in[9];
    const float* b_out = (const float*)d_in[10];

    float* out = (float*)d_out;                 // n_out: N*2, then n_embed: N*128
    float* emb = out + (size_t)N_NODES * 2;

    char* ws = (char*)d_ws;
    float* norm_src  = (float*)(ws + 0);             // 200192
    float* norm_dst  = (float*)(ws + 200192);        // 200192
    int*   deg_in    = (int*)(ws + 400384);          // 200192
    int*   row_start = (int*)(ws + 600576);          // 200704 (N+1 ints)
    int*   cursor    = (int*)(ws + 801280);          // 200192
    int*   partials98= (int*)(ws + 1001472);         // 512
    int2*  csr       = (int2*)(ws + 1001984);        // 6,400,000
    float* bufA      = (float*)(ws + 7401984);       // 25,600,000
    float* bufB      = (float*)(ws + 33001984);      // 25,600,000  (end 58.6 MB)
    // partO/partI (12.8 MB each) alias bufA exactly; dead before gather1 writes bufA.
    unsigned int* partO = (unsigned int*)bufA;
    unsigned int* partI = partO + (size_t)NB_HIST * WORDS;

    const int gridW = (N_NODES * 64 + 255) / 256;      // 12500 (wave per node)
    const int gridF = GRID_G + (N_EDGES + 255) / 256;  // gemm + fill blocks

    k_hist<<<NB_HIST, 256, 0, stream>>>(src, dst, partO, partI);
    k_normB<<<NORMB_BLOCKS, 256, 0, stream>>>(partO, partI, norm_src, norm_dst,
                                              deg_in, partials98);
    k_scan<<<NORMB_BLOCKS, 256, 0, stream>>>(deg_in, partials98, row_start, cursor);
    // GEMM1 (x@W1, graph-independent) fused with CSR fill
    k_gemm_fill<<<gridF, 256, 0, stream>>>(x, W1, bufB, src, dst, norm_src,
                                           cursor, csr);
    k_gather<1, 0><<<gridW, 256, 0, stream>>>(bufB, row_start, csr, norm_dst, b1,
                                              bufA, nullptr, nullptr, nullptr);
    k_gemm<<<GRID_G, 256, 0, stream>>>(bufA, W2, bufB);
    k_gather<1, 0><<<gridW, 256, 0, stream>>>(bufB, row_start, csr, norm_dst, b2,
                                              bufA, nullptr, nullptr, nullptr);
    k_gemm<<<GRID_G, 256, 0, stream>>>(bufA, W3, bufB);
    k_gather<0, 1><<<gridW, 256, 0, stream>>>(bufB, row_start, csr, norm_dst, b3,
                                              emb, W_out, b_out, out);
}

// Round 16
// 323.290 us; speedup vs baseline: 1.2801x; 1.0069x over previous
//
#include <hip/hip_runtime.h>

#define N_NODES 50000
#define N_EDGES 800000
#define GRID_G 782        // ceil(N_NODES/64) gemm blocks (64 rows/block; round-8 best)
#define NB_HIST 128       // histogram blocks
#define EPB (N_EDGES / NB_HIST)   // 6250 edges per hist block
#define WORDS 25000       // N_NODES/2 packed 2x16 words
#define NORMB_BLOCKS 98   // ceil(WORDS/256); each covers 512 nodes

typedef float f4 __attribute__((ext_vector_type(4)));  // native vec for nontemporal builtins

// ---------------- histogram degree count (no global atomics) ----------------
__global__ __launch_bounds__(256) void k_hist(const int* __restrict__ src,
                                              const int* __restrict__ dst,
                                              unsigned int* __restrict__ partO,
                                              unsigned int* __restrict__ partI) {
    __shared__ unsigned int h[12500];   // 50 KB: 25000 nodes packed 2 per word
    const int e0 = blockIdx.x * EPB;
    for (int kind = 0; kind < 2; ++kind) {
        const int* ids = kind ? dst : src;
        unsigned int* out = kind ? partI : partO;
        for (int p = 0; p < 2; ++p) {
            for (int i = threadIdx.x; i < 12500; i += 256) h[i] = 0;
            __syncthreads();
            const int base = p * 25000;
            for (int i = threadIdx.x; i < EPB; i += 256) {
                int id = ids[e0 + i] - base;
                if ((unsigned)id < 25000u)
                    atomicAdd(&h[id >> 1], (id & 1) ? 0x10000u : 1u);
            }
            __syncthreads();
            unsigned int* o = out + blockIdx.x * WORDS + p * 12500;
            for (int i = threadIdx.x; i < 12500; i += 256) o[i] = h[i];
            __syncthreads();
        }
    }
}

// ---------------- reduce partials -> degrees, norms, scan block-sums ----------------
__global__ __launch_bounds__(256) void k_normB(const unsigned int* __restrict__ partO,
                                               const unsigned int* __restrict__ partI,
                                               float* __restrict__ norm_src,
                                               float* __restrict__ norm_dst,
                                               int* __restrict__ deg_in,
                                               int* __restrict__ partials98) {
    __shared__ int sm4[4];
    int w = blockIdx.x * 256 + threadIdx.x;
    unsigned int lo_o = 0, hi_o = 0, lo_i = 0, hi_i = 0;
    if (w < WORDS) {
        for (int b = 0; b < NB_HIST; ++b) {
            unsigned int vo = partO[b * WORDS + w];
            unsigned int vi = partI[b * WORDS + w];
            lo_o += vo & 0xFFFFu; hi_o += vo >> 16;
            lo_i += vi & 0xFFFFu; hi_i += vi >> 16;
        }
        int n0 = 2 * w;
        *(float2*)&norm_src[n0] = make_float2(rsqrtf((float)max(lo_o, 1u)),
                                              rsqrtf((float)max(hi_o, 1u)));
        *(float2*)&norm_dst[n0] = make_float2(rsqrtf((float)max(lo_i, 1u)),
                                              rsqrtf((float)max(hi_i, 1u)));
        *(int2*)&deg_in[n0] = make_int2((int)lo_i, (int)hi_i);
    }
    int v = (int)(lo_i + hi_i);
#pragma unroll
    for (int off = 32; off > 0; off >>= 1) v += __shfl_down(v, off);
    int lane = threadIdx.x & 63, wv = threadIdx.x >> 6;
    if (lane == 0) sm4[wv] = v;
    __syncthreads();
    if (threadIdx.x == 0)
        partials98[blockIdx.x] = sm4[0] + sm4[1] + sm4[2] + sm4[3];
}

// ---------------- scan: exclusive prefix over deg_in (512 nodes/block) ----------------
__global__ __launch_bounds__(256) void k_scan(const int* __restrict__ deg_in,
                                              const int* __restrict__ partials98,
                                              int* __restrict__ row_start,
                                              int* __restrict__ cursor) {
    __shared__ int sm[256];
    __shared__ int carry_s;
    int t = threadIdx.x;
    if (t < 64) {
        int acc = 0;
        for (int i = t; i < blockIdx.x; i += 64) acc += partials98[i];
#pragma unroll
        for (int off = 32; off > 0; off >>= 1) acc += __shfl_down(acc, off);
        if (t == 0) carry_s = acc;
    }
    int n0 = blockIdx.x * 512 + t * 2;
    int a0 = 0, a1 = 0;
    if (n0 + 1 < N_NODES) {
        int2 d = *(const int2*)&deg_in[n0];
        a0 = d.x; a1 = d.y;
    } else if (n0 < N_NODES) {
        a0 = deg_in[n0];
    }
    sm[t] = a0 + a1;
    __syncthreads();
#pragma unroll
    for (int off = 1; off < 256; off <<= 1) {
        int tv = (t >= off) ? sm[t - off] : 0;
        __syncthreads();
        sm[t] += tv;
        __syncthreads();
    }
    int excl = sm[t] - (a0 + a1) + carry_s;
    if (n0 < N_NODES) { row_start[n0] = excl; cursor[n0] = excl; }
    if (n0 + 1 < N_NODES) { row_start[n0 + 1] = excl + a0; cursor[n0 + 1] = excl + a0; }
    if (blockIdx.x == 0 && t == 0) row_start[N_NODES] = N_EDGES;
}

// ---------------- GEMM body: G = X @ W (N,128)x(128,128) ----------------
// Round-8 tile (best measured): 64 rows/block, thread 4x8 (c0/c0+64), W in two
// 32 KB chunks. G stores are NON-TEMPORAL (native f4 vec; HIP float4 is a class
// the builtin rejects -- round-15 compile fail): G's L2 residency is worthless
// (next gather reads mostly cross-XCD via L3), and inside k_gemm_fill the
// 25.6 MB G stream was evicting partially-filled csr lines from L2 ->
// ~51 MB write amplification on a 6.4 MB buffer (round-14 WRITE_SIZE=77MB).
__device__ __forceinline__ void gemm_body(const float* __restrict__ X,
                                          const float* __restrict__ W,
                                          float* __restrict__ G,
                                          float* __restrict__ Wl, int bid) {
    const int tx = threadIdx.x & 15;
    const int ty = threadIdx.x >> 4;
    const int r0 = bid * 64 + ty * 4;
    const int c0 = tx * 4;

    const float* xr[4];
#pragma unroll
    for (int i = 0; i < 4; ++i) {
        int r = r0 + i; if (r > N_NODES - 1) r = N_NODES - 1;
        xr[i] = X + (size_t)r * 128;
    }

    float acc[2][4][4] = {};
    for (int kc = 0; kc < 2; ++kc) {
        __syncthreads();
#pragma unroll
        for (int it = 0; it < 8; ++it) {
            int idx = threadIdx.x * 4 + it * 1024;
            *(float4*)&Wl[idx] = *(const float4*)&W[kc * 8192 + idx];
        }
        __syncthreads();
        const int kb = kc * 64;
#pragma unroll
        for (int kq = 0; kq < 4; ++kq) {          // 16-k batches
            float4 xa[4][4];
#pragma unroll
            for (int j = 0; j < 4; ++j)
#pragma unroll
                for (int i = 0; i < 4; ++i)
                    xa[i][j] = *(const float4*)(xr[i] + kb + kq * 16 + j * 4);
#pragma unroll
            for (int j = 0; j < 4; ++j) {
                const int ks = kq * 16 + j * 4;
#pragma unroll
                for (int kk = 0; kk < 4; ++kk) {
                    float4 w0 = *(const float4*)&Wl[(ks + kk) * 128 + c0];
                    float4 w1 = *(const float4*)&Wl[(ks + kk) * 128 + c0 + 64];
#pragma unroll
                    for (int i = 0; i < 4; ++i) {
                        float a = (kk == 0) ? xa[i][j].x : (kk == 1) ? xa[i][j].y
                                 : (kk == 2) ? xa[i][j].z : xa[i][j].w;
                        acc[0][i][0] = fmaf(a, w0.x, acc[0][i][0]);
                        acc[0][i][1] = fmaf(a, w0.y, acc[0][i][1]);
                        acc[0][i][2] = fmaf(a, w0.z, acc[0][i][2]);
                        acc[0][i][3] = fmaf(a, w0.w, acc[0][i][3]);
                        acc[1][i][0] = fmaf(a, w1.x, acc[1][i][0]);
                        acc[1][i][1] = fmaf(a, w1.y, acc[1][i][1]);
                        acc[1][i][2] = fmaf(a, w1.z, acc[1][i][2]);
                        acc[1][i][3] = fmaf(a, w1.w, acc[1][i][3]);
                    }
                }
            }
        }
    }
#pragma unroll
    for (int i = 0; i < 4; ++i) {
        int r = r0 + i;
        if (r < N_NODES) {
            f4* p = (f4*)(G + (size_t)r * 128 + c0);
            f4 v0 = {acc[0][i][0], acc[0][i][1], acc[0][i][2], acc[0][i][3]};
            f4 v1 = {acc[1][i][0], acc[1][i][1], acc[1][i][2], acc[1][i][3]};
            __builtin_nontemporal_store(v0, p);        // cols c0..c0+3
            __builtin_nontemporal_store(v1, p + 16);   // cols c0+64.. (16 f4 = 64 floats)
        }
    }
}

__global__ __launch_bounds__(256, 4) void k_gemm(const float* __restrict__ X,
                                                 const float* __restrict__ W,
                                                 float* __restrict__ G) {
    __shared__ float Wl[8192];
    gemm_body(X, W, G, Wl, blockIdx.x);
}

// ---------------- fused: GEMM1 (graph-independent) + CSR fill ----------------
__global__ __launch_bounds__(256, 4) void k_gemm_fill(const float* __restrict__ X,
                                                      const float* __restrict__ W,
                                                      float* __restrict__ G,
                                                      const int* __restrict__ src,
                                                      const int* __restrict__ dst,
                                                      const float* __restrict__ norm_src,
                                                      int* __restrict__ cursor,
                                                      int2* __restrict__ csr) {
    __shared__ float Wl[8192];
    if (blockIdx.x < GRID_G) {
        gemm_body(X, W, G, Wl, blockIdx.x);
    } else {
        int e = (blockIdx.x - GRID_G) * 256 + threadIdx.x;
        if (e < N_EDGES) {
            int d = dst[e], s = src[e];
            int pos = atomicAdd(&cursor[d], 1);
            csr[pos] = make_int2(s, __float_as_int(norm_src[s]));
        }
    }
}

// ---------------- gather: Out[n] = act(norm_dst[n] * sum_e w_e * G[src_e] + b) ----------------
// Round-8 form (best measured): one wave per node, edge-pair scheme (lanes 0-31 even
// edges, 32-63 odd, float4 cols l*4..l*4+3, shfl_xor(32) combine), 8-wide loop.
template <int ELU, int PROJ>
__global__ __launch_bounds__(256) void k_gather(const float* __restrict__ G,
                                                const int* __restrict__ row_start,
                                                const int2* __restrict__ csr,
                                                const float* __restrict__ norm_dst,
                                                const float* __restrict__ bias,
                                                float* __restrict__ Out,
                                                const float* __restrict__ Wo,
                                                const float* __restrict__ bo,
                                                float* __restrict__ proj_out) {
    int n = (blockIdx.x * 256 + threadIdx.x) >> 6;
    int lane = threadIdx.x & 63;
    if (n >= N_NODES) return;
    const int half = lane >> 5;
    const int l = lane & 31;
    int e0 = row_start[n], e1 = row_start[n + 1];
    float4 a0 = {0,0,0,0}, a1 = {0,0,0,0}, a2 = {0,0,0,0}, a3 = {0,0,0,0};
    int e = e0;
    for (; e + 8 <= e1; e += 8) {
        int2 c0 = csr[e + half],     c1 = csr[e + 2 + half];
        int2 c2 = csr[e + 4 + half], c3 = csr[e + 6 + half];
        float4 g0 = *(const float4*)(G + (size_t)c0.x * 128 + l * 4);
        float4 g1 = *(const float4*)(G + (size_t)c1.x * 128 + l * 4);
        float4 g2 = *(const float4*)(G + (size_t)c2.x * 128 + l * 4);
        float4 g3 = *(const float4*)(G + (size_t)c3.x * 128 + l * 4);
        float w0 = __int_as_float(c0.y), w1 = __int_as_float(c1.y);
        float w2 = __int_as_float(c2.y), w3 = __int_as_float(c3.y);
        a0.x = fmaf(w0, g0.x, a0.x); a0.y = fmaf(w0, g0.y, a0.y);
        a0.z = fmaf(w0, g0.z, a0.z); a0.w = fmaf(w0, g0.w, a0.w);
        a1.x = fmaf(w1, g1.x, a1.x); a1.y = fmaf(w1, g1.y, a1.y);
        a1.z = fmaf(w1, g1.z, a1.z); a1.w = fmaf(w1, g1.w, a1.w);
        a2.x = fmaf(w2, g2.x, a2.x); a2.y = fmaf(w2, g2.y, a2.y);
        a2.z = fmaf(w2, g2.z, a2.z); a2.w = fmaf(w2, g2.w, a2.w);
        a3.x = fmaf(w3, g3.x, a3.x); a3.y = fmaf(w3, g3.y, a3.y);
        a3.z = fmaf(w3, g3.z, a3.z); a3.w = fmaf(w3, g3.w, a3.w);
    }
    for (; e < e1; e += 2) {
        int idx = e + half;
        if (idx < e1) {
            int2 c = csr[idx];
            float w = __int_as_float(c.y);
            float4 g = *(const float4*)(G + (size_t)c.x * 128 + l * 4);
            a0.x = fmaf(w, g.x, a0.x); a0.y = fmaf(w, g.y, a0.y);
            a0.z = fmaf(w, g.z, a0.z); a0.w = fmaf(w, g.w, a0.w);
        }
    }
    float4 s;
    s.x = (a0.x + a1.x) + (a2.x + a3.x);
    s.y = (a0.y + a1.y) + (a2.y + a3.y);
    s.z = (a0.z + a1.z) + (a2.z + a3.z);
    s.w = (a0.w + a1.w) + (a2.w + a3.w);
    s.x += __shfl_xor(s.x, 32);
    s.y += __shfl_xor(s.y, 32);
    s.z += __shfl_xor(s.z, 32);
    s.w += __shfl_xor(s.w, 32);
    float nd = norm_dst[n];
    float4 b = *(const float4*)(bias + l * 4);
    float4 o;
    o.x = fmaf(nd, s.x, b.x);
    o.y = fmaf(nd, s.y, b.y);
    o.z = fmaf(nd, s.z, b.z);
    o.w = fmaf(nd, s.w, b.w);
    if (ELU) {
        o.x = o.x > 0.f ? o.x : expm1f(o.x);
        o.y = o.y > 0.f ? o.y : expm1f(o.y);
        o.z = o.z > 0.f ? o.z : expm1f(o.z);
        o.w = o.w > 0.f ? o.w : expm1f(o.w);
    }
    if (half == 0)
        *(float4*)(Out + (size_t)n * 128 + l * 4) = o;
    if (PROJ) {
        float p0 = o.x * Wo[(l * 4 + 0) * 2] + o.y * Wo[(l * 4 + 1) * 2]
                 + o.z * Wo[(l * 4 + 2) * 2] + o.w * Wo[(l * 4 + 3) * 2];
        float p1 = o.x * Wo[(l * 4 + 0) * 2 + 1] + o.y * Wo[(l * 4 + 1) * 2 + 1]
                 + o.z * Wo[(l * 4 + 2) * 2 + 1] + o.w * Wo[(l * 4 + 3) * 2 + 1];
#pragma unroll
        for (int off = 16; off > 0; off >>= 1) {
            p0 += __shfl_down(p0, off);
            p1 += __shfl_down(p1, off);
        }
        if (lane == 0) {
            proj_out[n * 2 + 0] = p0 + bo[0];
            proj_out[n * 2 + 1] = p1 + bo[1];
        }
    }
}

extern "C" void kernel_launch(void* const* d_in, const int* in_sizes, int n_in,
                              void* d_out, int out_size, void* d_ws, size_t ws_size,
                              hipStream_t stream) {
    const float* x     = (const float*)d_in[0];
    const int*   src   = (const int*)d_in[1];
    const int*   dst   = (const int*)d_in[2];
    const float* W1    = (const float*)d_in[3];
    const float* b1    = (const float*)d_in[4];
    const float* W2    = (const float*)d_in[5];
    const float* b2    = (const float*)d_in[6];
    const float* W3    = (const float*)d_in[7];
    const float* b3    = (const float*)d_in[8];
    const float* W_out = (const float*)d_in[9];
    const float* b_out = (const float*)d_in[10];

    float* out = (float*)d_out;                 // n_out: N*2, then n_embed: N*128
    float* emb = out + (size_t)N_NODES * 2;

    char* ws = (char*)d_ws;
    float* norm_src  = (float*)(ws + 0);             // 200192
    float* norm_dst  = (float*)(ws + 200192);        // 200192
    int*   deg_in    = (int*)(ws + 400384);          // 200192
    int*   row_start = (int*)(ws + 600576);          // 200704 (N+1 ints)
    int*   cursor    = (int*)(ws + 801280);          // 200192
    int*   partials98= (int*)(ws + 1001472);         // 512
    int2*  csr       = (int2*)(ws + 1001984);        // 6,400,000
    float* bufA      = (float*)(ws + 7401984);       // 25,600,000
    float* bufB      = (float*)(ws + 33001984);      // 25,600,000  (end 58.6 MB)
    // partO/partI (12.8 MB each) alias bufA exactly; dead before gather1 writes bufA.
    unsigned int* partO = (unsigned int*)bufA;
    unsigned int* partI = partO + (size_t)NB_HIST * WORDS;

    const int gridW = (N_NODES * 64 + 255) / 256;      // 12500 (wave per node)
    const int gridF = GRID_G + (N_EDGES + 255) / 256;  // gemm + fill blocks

    k_hist<<<NB_HIST, 256, 0, stream>>>(src, dst, partO, partI);
    k_normB<<<NORMB_BLOCKS, 256, 0, stream>>>(partO, partI, norm_src, norm_dst,
                                              deg_in, partials98);
    k_scan<<<NORMB_BLOCKS, 256, 0, stream>>>(deg_in, partials98, row_start, cursor);
    // GEMM1 (x@W1, graph-independent) fused with CSR fill
    k_gemm_fill<<<gridF, 256, 0, stream>>>(x, W1, bufB, src, dst, norm_src,
                                           cursor, csr);
    k_gather<1, 0><<<gridW, 256, 0, stream>>>(bufB, row_start, csr, norm_dst, b1,
                                              bufA, nullptr, nullptr, nullptr);
    k_gemm<<<GRID_G, 256, 0, stream>>>(bufA, W2, bufB);
    k_gather<1, 0><<<gridW, 256, 0, stream>>>(bufB, row_start, csr, norm_dst, b2,
                                              bufA, nullptr, nullptr, nullptr);
    k_gemm<<<GRID_G, 256, 0, stream>>>(bufA, W3, bufB);
    k_gather<0, 1><<<gridW, 256, 0, stream>>>(bufB, row_start, csr, norm_dst, b3,
                                              emb, W_out, b_out, out);
}